// Round 2
// baseline (1044.875 us; speedup 1.0000x reference)
//
#include <hip/hip_runtime.h>
#include <hip/hip_bf16.h>
#include <math.h>

#define L_SEQ 2048
#define DMODEL 2048
#define PROJW 3072
#define NQH 32
#define NKVH 8
#define HD 64
#define SW 512

typedef __attribute__((ext_vector_type(8))) short bf16x8;
typedef __attribute__((ext_vector_type(4))) float f32x4;

__device__ __forceinline__ ushort f2bf(float x) {
    __hip_bfloat16 h = __float2bfloat16(x);
    return *reinterpret_cast<ushort*>(&h);
}
__device__ __forceinline__ float bf2f(ushort u) {
    __hip_bfloat16 h = *reinterpret_cast<__hip_bfloat16*>(&u);
    return __bfloat162float(h);
}

__device__ __forceinline__ void glds16(const void* g, void* l) {
    __builtin_amdgcn_global_load_lds(
        (__attribute__((address_space(1))) void*)(void*)g,
        (__attribute__((address_space(3))) void*)l, 16, 0, 0);
}

// ---------------- RoPE tables: cos/sin (L x 32) ----------------
__global__ void rope_tables_kernel(float* __restrict__ cosT, float* __restrict__ sinT) {
    int pos = blockIdx.x * blockDim.x + threadIdx.x;
    if (pos >= L_SEQ) return;
    #pragma unroll
    for (int j = 0; j < 32; ++j) {
        float c, s;
        if (j < 16) {
            float t = (float)j * (1.0f / 15.0f);
            float freq = powf(1.0f / 1024.0f, t);
            float th = (float)pos * freq;
            sincosf(th, &s, &c);
        } else {
            c = 1.0f; s = 0.0f;
        }
        cosT[pos * 32 + j] = c;
        sinT[pos * 32 + j] = s;
    }
}

// ---------------- RoPE apply, in-place on proj ----------------
__global__ void rope_apply_kernel(float* __restrict__ proj,
                                  const float* __restrict__ cosT,
                                  const float* __restrict__ sinT) {
    int pos = blockIdx.x;
    const float* ct = cosT + pos * 32;
    const float* st = sinT + pos * 32;
    float* row = proj + (size_t)pos * PROJW;
    for (int p = threadIdx.x; p < 40 * 32; p += blockDim.x) {
        int head = p >> 5;
        int d = p & 31;
        int base = (head < NQH) ? head * HD : DMODEL + (head - NQH) * HD;
        float x1 = row[base + d];
        float x2 = row[base + d + 32];
        float c = ct[d], s = st[d];
        row[base + d]      = x1 * c + x2 * s;
        row[base + d + 32] = -x1 * s + x2 * c;
    }
}

// ---------------- fp32 -> bf16 hi/lo split, same layout ----------------
__global__ __launch_bounds__(256) void split_rm_kernel(const float* __restrict__ A,
                                                       ushort* __restrict__ hi,
                                                       ushort* __restrict__ lo) {
    int i = (blockIdx.x * 256 + threadIdx.x) * 4;
    float4 v = *reinterpret_cast<const float4*>(&A[i]);
    float vv[4] = {v.x, v.y, v.z, v.w};
    ushort h[4], l[4];
    #pragma unroll
    for (int j = 0; j < 4; ++j) {
        h[j] = f2bf(vv[j]);
        l[j] = f2bf(vv[j] - bf2f(h[j]));
    }
    *reinterpret_cast<ushort4*>(&hi[i]) = make_ushort4(h[0], h[1], h[2], h[3]);
    *reinterpret_cast<ushort4*>(&lo[i]) = make_ushort4(l[0], l[1], l[2], l[3]);
}

// ---------------- fp32 W(KxN) -> bf16 hi/lo transposed Wt(NxK) ----------------
__global__ __launch_bounds__(256) void split_t_kernel(const float* __restrict__ W,
                                                      ushort* __restrict__ hi,
                                                      ushort* __restrict__ lo,
                                                      int K, int N) {
    __shared__ float t[32][33];
    int n0 = blockIdx.x * 32, k0 = blockIdx.y * 32;
    int tx = threadIdx.x & 31, ty = threadIdx.x >> 5;   // ty 0..7
    #pragma unroll
    for (int r = 0; r < 32; r += 8)
        t[ty + r][tx] = W[(size_t)(k0 + ty + r) * N + n0 + tx];
    __syncthreads();
    #pragma unroll
    for (int r = 0; r < 32; r += 8) {
        float v = t[tx][ty + r];                        // = W[k0+tx][n0+ty+r]
        ushort h = f2bf(v);
        ushort l = f2bf(v - bf2f(h));
        size_t o = (size_t)(n0 + ty + r) * K + k0 + tx; // Wt[n][k]
        hi[o] = h;
        lo[o] = l;
    }
}

// ---------------- bf16x2 MFMA GEMM: C(MxN) = A(MxK) @ Bt(NxK)^T, fp32 out --------
// 128x128 tile, BK=32, 4 waves (2x2), each wave 64x64 = 4x4 fragments of 16x16x32.
// Error-compensated: C += Ahi*Bhi + Ahi*Blo + Alo*Bhi  (3 MFMA / fragment pair).
// LDS linear [row][32k] via global_load_lds w=16; chunk-XOR swizzle (kc ^= row&3)
// applied on the staging SOURCE address and on the fragment READ (Guideline 21).
#define GBK 32

__global__ __launch_bounds__(256) void gemm_bf16x2_kernel(
    const ushort* __restrict__ Ahi, const ushort* __restrict__ Alo,
    const ushort* __restrict__ Bhi, const ushort* __restrict__ Blo,
    float* __restrict__ C, int M, int N, int K)
{
    __shared__ __align__(16) ushort sAh[128 * 32];
    __shared__ __align__(16) ushort sAl[128 * 32];
    __shared__ __align__(16) ushort sBh[128 * 32];
    __shared__ __align__(16) ushort sBl[128 * 32];

    const int tid = threadIdx.x;
    const int w = tid >> 6, lane = tid & 63;
    const int bm = blockIdx.y * 128, bn = blockIdx.x * 128;
    const int wr = w >> 1, wc = w & 1;

    f32x4 acc[4][4];
    #pragma unroll
    for (int i = 0; i < 4; ++i)
        #pragma unroll
        for (int j = 0; j < 4; ++j)
            acc[i][j] = (f32x4){0.0f, 0.0f, 0.0f, 0.0f};

    // staging: 512 chunks of 16B per buffer; wave w owns chunks [w*128, w*128+128)
    const int q0 = w * 128 + lane;
    const int q1 = q0 + 64;
    const int r0 = q0 >> 2, r1 = q1 >> 2;
    const int ks0 = ((q0 & 3) ^ (r0 & 3)) * 8;   // source-side swizzle
    const int ks1 = ((q1 & 3) ^ (r1 & 3)) * 8;
    const ushort* gAh0 = Ahi + (size_t)(bm + r0) * K + ks0;
    const ushort* gAh1 = Ahi + (size_t)(bm + r1) * K + ks1;
    const ushort* gAl0 = Alo + (size_t)(bm + r0) * K + ks0;
    const ushort* gAl1 = Alo + (size_t)(bm + r1) * K + ks1;
    const ushort* gBh0 = Bhi + (size_t)(bn + r0) * K + ks0;
    const ushort* gBh1 = Bhi + (size_t)(bn + r1) * K + ks1;
    const ushort* gBl0 = Blo + (size_t)(bn + r0) * K + ks0;
    const ushort* gBl1 = Blo + (size_t)(bn + r1) * K + ks1;
    ushort* dAh0 = sAh + (w * 2 + 0) * 512;  // 1024B per instr, wave-uniform
    ushort* dAh1 = sAh + (w * 2 + 1) * 512;
    ushort* dAl0 = sAl + (w * 2 + 0) * 512;
    ushort* dAl1 = sAl + (w * 2 + 1) * 512;
    ushort* dBh0 = sBh + (w * 2 + 0) * 512;
    ushort* dBh1 = sBh + (w * 2 + 1) * 512;
    ushort* dBl0 = sBl + (w * 2 + 0) * 512;
    ushort* dBl1 = sBl + (w * 2 + 1) * 512;

    const int kg = lane >> 4;          // fragment k-group 0..3
    const int fr = lane & 15;          // fragment row/col

    for (int k0 = 0; k0 < K; k0 += GBK) {
        __syncthreads();               // consumers of previous tile done
        glds16(gAh0 + k0, dAh0);
        glds16(gAh1 + k0, dAh1);
        glds16(gBh0 + k0, dBh0);
        glds16(gBh1 + k0, dBh1);
        glds16(gAl0 + k0, dAl0);
        glds16(gAl1 + k0, dAl1);
        glds16(gBl0 + k0, dBl0);
        glds16(gBl1 + k0, dBl1);
        __syncthreads();               // vmcnt(0) drain -> tile visible

        bf16x8 ah[4], al[4], bh[4], bl[4];
        #pragma unroll
        for (int i = 0; i < 4; ++i) {
            int row = wr * 64 + i * 16 + fr;
            int off = row * 32 + ((kg ^ (row & 3)) * 8);   // read-side swizzle
            ah[i] = *reinterpret_cast<const bf16x8*>(&sAh[off]);
            al[i] = *reinterpret_cast<const bf16x8*>(&sAl[off]);
        }
        #pragma unroll
        for (int j = 0; j < 4; ++j) {
            int row = wc * 64 + j * 16 + fr;
            int off = row * 32 + ((kg ^ (row & 3)) * 8);
            bh[j] = *reinterpret_cast<const bf16x8*>(&sBh[off]);
            bl[j] = *reinterpret_cast<const bf16x8*>(&sBl[off]);
        }
        #pragma unroll
        for (int i = 0; i < 4; ++i)
            #pragma unroll
            for (int j = 0; j < 4; ++j) {
                acc[i][j] = __builtin_amdgcn_mfma_f32_16x16x32_bf16(ah[i], bh[j], acc[i][j], 0, 0, 0);
                acc[i][j] = __builtin_amdgcn_mfma_f32_16x16x32_bf16(ah[i], bl[j], acc[i][j], 0, 0, 0);
                acc[i][j] = __builtin_amdgcn_mfma_f32_16x16x32_bf16(al[i], bh[j], acc[i][j], 0, 0, 0);
            }
    }

    // C/D layout (m89-verified): col = lane&15, row = (lane>>4)*4 + reg
    const int rq = (lane >> 4) * 4;
    #pragma unroll
    for (int i = 0; i < 4; ++i)
        #pragma unroll
        for (int j = 0; j < 4; ++j) {
            #pragma unroll
            for (int q = 0; q < 4; ++q) {
                C[(size_t)(bm + wr * 64 + i * 16 + rq + q) * N + bn + wc * 64 + j * 16 + fr]
                    = acc[i][j][q];
            }
        }
}

// ---------------- GQA attention (fp32 flash), writes bf16 hi/lo output ------------
__global__ __launch_bounds__(256) void attn_kernel(const float* __restrict__ proj,
                                                   const float* __restrict__ sink,
                                                   ushort* __restrict__ out_hi,
                                                   ushort* __restrict__ out_lo) {
    __shared__ float Qs[64][68];
    __shared__ float Ks[64][68];
    __shared__ float Vs[64][68];
    __shared__ float Ps[64][68];

    const int tid = threadIdx.x;
    const int q0 = blockIdx.x * 64;
    const int hq = blockIdx.y;          // 0..31  (= h*4 + m)
    const int h  = hq >> 2;
    const int qcb = hq * HD;
    const int kcb = DMODEL + h * HD;
    const int vcb = DMODEL + NKVH * HD + h * HD;
    const int g  = tid & 7;
    const int rp = tid >> 3;
    const int r0 = rp * 2, r1 = r0 + 1;
    const int qa = q0 + r0, qb = q0 + r1;

    {   // load Q tile 64x64
        int row = tid >> 2, cg = (tid & 3) * 16;
        const float* src = proj + (size_t)(q0 + row) * PROJW + qcb + cg;
        #pragma unroll
        for (int i = 0; i < 4; ++i) {
            float4 v = reinterpret_cast<const float4*>(src)[i];
            *reinterpret_cast<float4*>(&Qs[row][cg + 4 * i]) = v;
        }
    }

    const float sval = sink[hq];
    float m0 = sval, m1 = sval, l0 = 1.0f, l1 = 1.0f;
    float o0[8], o1[8];
    #pragma unroll
    for (int i = 0; i < 8; ++i) { o0[i] = 0.0f; o1[i] = 0.0f; }

    const int krow = tid >> 2, kcg = (tid & 3) * 16;
    __syncthreads();

    for (int k0 = 0; k0 < L_SEQ; k0 += 64) {
        // inverted mask: masked(q,k) = (q>=k) && (q<k+SW). Tile all-masked -> skip.
        if ((q0 >= k0 + 63) && (q0 + 63 < k0 + SW)) continue;

        float4 kv[4], vv[4];
        {
            const float* ksrc = proj + (size_t)(k0 + krow) * PROJW + kcb + kcg;
            const float* vsrc = proj + (size_t)(k0 + krow) * PROJW + vcb + kcg;
            #pragma unroll
            for (int i = 0; i < 4; ++i) {
                kv[i] = reinterpret_cast<const float4*>(ksrc)[i];
                vv[i] = reinterpret_cast<const float4*>(vsrc)[i];
            }
        }
        __syncthreads();
        #pragma unroll
        for (int i = 0; i < 4; ++i) {
            *reinterpret_cast<float4*>(&Ks[krow][kcg + 4 * i]) = kv[i];
            *reinterpret_cast<float4*>(&Vs[krow][kcg + 4 * i]) = vv[i];
        }
        __syncthreads();

        float sc0[8], sc1[8];
        #pragma unroll
        for (int j = 0; j < 8; ++j) { sc0[j] = 0.0f; sc1[j] = 0.0f; }
        #pragma unroll
        for (int d = 0; d < HD; d += 4) {
            float4 qva = *reinterpret_cast<const float4*>(&Qs[r0][d]);
            float4 qvb = *reinterpret_cast<const float4*>(&Qs[r1][d]);
            #pragma unroll
            for (int j = 0; j < 8; ++j) {
                float4 kk = *reinterpret_cast<const float4*>(&Ks[g + 8 * j][d]);
                sc0[j] += qva.x * kk.x + qva.y * kk.y + qva.z * kk.z + qva.w * kk.w;
                sc1[j] += qvb.x * kk.x + qvb.y * kk.y + qvb.z * kk.z + qvb.w * kk.w;
            }
        }

        float tm0 = -INFINITY, tm1 = -INFINITY;
        #pragma unroll
        for (int j = 0; j < 8; ++j) {
            int k = k0 + g + 8 * j;
            float s0 = sc0[j] * 0.125f;
            float s1 = sc1[j] * 0.125f;
            if ((qa >= k) && (qa < k + SW)) s0 = -INFINITY;
            if ((qb >= k) && (qb < k + SW)) s1 = -INFINITY;
            sc0[j] = s0; sc1[j] = s1;
            tm0 = fmaxf(tm0, s0);
            tm1 = fmaxf(tm1, s1);
        }
        #pragma unroll
        for (int off = 1; off < 8; off <<= 1) {
            tm0 = fmaxf(tm0, __shfl_xor(tm0, off, 64));
            tm1 = fmaxf(tm1, __shfl_xor(tm1, off, 64));
        }
        float mn0 = fmaxf(m0, tm0);
        float mn1 = fmaxf(m1, tm1);
        float al0 = expf(m0 - mn0);
        float al1 = expf(m1 - mn1);
        float ps0 = 0.0f, ps1 = 0.0f;
        #pragma unroll
        for (int j = 0; j < 8; ++j) {
            float p0 = expf(sc0[j] - mn0);
            float p1 = expf(sc1[j] - mn1);
            Ps[r0][g + 8 * j] = p0;
            Ps[r1][g + 8 * j] = p1;
            ps0 += p0; ps1 += p1;
        }
        #pragma unroll
        for (int off = 1; off < 8; off <<= 1) {
            ps0 += __shfl_xor(ps0, off, 64);
            ps1 += __shfl_xor(ps1, off, 64);
        }
        l0 = l0 * al0 + ps0;
        l1 = l1 * al1 + ps1;
        m0 = mn0; m1 = mn1;
        #pragma unroll
        for (int i = 0; i < 8; ++i) { o0[i] *= al0; o1[i] *= al1; }
        __syncthreads();

        #pragma unroll
        for (int k = 0; k < 64; k += 4) {
            float4 p0v = *reinterpret_cast<const float4*>(&Ps[r0][k]);
            float4 p1v = *reinterpret_cast<const float4*>(&Ps[r1][k]);
            float p0a[4] = {p0v.x, p0v.y, p0v.z, p0v.w};
            float p1a[4] = {p1v.x, p1v.y, p1v.z, p1v.w};
            #pragma unroll
            for (int kk = 0; kk < 4; ++kk) {
                float4 va = *reinterpret_cast<const float4*>(&Vs[k + kk][g * 8]);
                float4 vb = *reinterpret_cast<const float4*>(&Vs[k + kk][g * 8 + 4]);
                float pa = p0a[kk], pb = p1a[kk];
                o0[0] = fmaf(pa, va.x, o0[0]); o0[1] = fmaf(pa, va.y, o0[1]);
                o0[2] = fmaf(pa, va.z, o0[2]); o0[3] = fmaf(pa, va.w, o0[3]);
                o0[4] = fmaf(pa, vb.x, o0[4]); o0[5] = fmaf(pa, vb.y, o0[5]);
                o0[6] = fmaf(pa, vb.z, o0[6]); o0[7] = fmaf(pa, vb.w, o0[7]);
                o1[0] = fmaf(pb, va.x, o1[0]); o1[1] = fmaf(pb, va.y, o1[1]);
                o1[2] = fmaf(pb, va.z, o1[2]); o1[3] = fmaf(pb, va.w, o1[3]);
                o1[4] = fmaf(pb, vb.x, o1[4]); o1[5] = fmaf(pb, vb.y, o1[5]);
                o1[6] = fmaf(pb, vb.z, o1[6]); o1[7] = fmaf(pb, vb.w, o1[7]);
            }
        }
    }

    const float inv0 = 1.0f / l0;
    const float inv1 = 1.0f / l1;
    ushort h8[8], l8[8];
    size_t ba = (size_t)qa * DMODEL + qcb + g * 8;
    size_t bb = (size_t)qb * DMODEL + qcb + g * 8;
    #pragma unroll
    for (int i = 0; i < 8; ++i) {
        float v = o0[i] * inv0;
        h8[i] = f2bf(v);
        l8[i] = f2bf(v - bf2f(h8[i]));
    }
    *reinterpret_cast<ushort4*>(&out_hi[ba])     = make_ushort4(h8[0], h8[1], h8[2], h8[3]);
    *reinterpret_cast<ushort4*>(&out_hi[ba + 4]) = make_ushort4(h8[4], h8[5], h8[6], h8[7]);
    *reinterpret_cast<ushort4*>(&out_lo[ba])     = make_ushort4(l8[0], l8[1], l8[2], l8[3]);
    *reinterpret_cast<ushort4*>(&out_lo[ba + 4]) = make_ushort4(l8[4], l8[5], l8[6], l8[7]);
    #pragma unroll
    for (int i = 0; i < 8; ++i) {
        float v = o1[i] * inv1;
        h8[i] = f2bf(v);
        l8[i] = f2bf(v - bf2f(h8[i]));
    }
    *reinterpret_cast<ushort4*>(&out_hi[bb])     = make_ushort4(h8[0], h8[1], h8[2], h8[3]);
    *reinterpret_cast<ushort4*>(&out_hi[bb + 4]) = make_ushort4(h8[4], h8[5], h8[6], h8[7]);
    *reinterpret_cast<ushort4*>(&out_lo[bb])     = make_ushort4(l8[0], l8[1], l8[2], l8[3]);
    *reinterpret_cast<ushort4*>(&out_lo[bb + 4]) = make_ushort4(l8[4], l8[5], l8[6], l8[7]);
}

extern "C" void kernel_launch(void* const* d_in, const int* in_sizes, int n_in,
                              void* d_out, int out_size, void* d_ws, size_t ws_size,
                              hipStream_t stream) {
    const float* x     = (const float*)d_in[0];
    const float* W_qkv = (const float*)d_in[1];
    const float* W_out = (const float*)d_in[2];
    const float* s     = (const float*)d_in[3];
    float* outp = (float*)d_out;

    // workspace layout (bytes) — total ~101 MB
    char* ws = (char*)d_ws;
    float*  proj = (float*)ws;  ws += (size_t)L_SEQ * PROJW * 4;     // 25.2 MB
    float*  cosT = (float*)ws;  ws += (size_t)L_SEQ * 32 * 4;
    float*  sinT = (float*)ws;  ws += (size_t)L_SEQ * 32 * 4;
    ushort* xh   = (ushort*)ws; ws += (size_t)L_SEQ * DMODEL * 2;    // x hi/lo
    ushort* xl   = (ushort*)ws; ws += (size_t)L_SEQ * DMODEL * 2;
    ushort* wqh  = (ushort*)ws; ws += (size_t)PROJW * DMODEL * 2;    // W_qkv^T hi/lo (N x K)
    ushort* wql  = (ushort*)ws; ws += (size_t)PROJW * DMODEL * 2;
    ushort* woh  = (ushort*)ws; ws += (size_t)DMODEL * DMODEL * 2;   // W_out^T hi/lo
    ushort* wol  = (ushort*)ws; ws += (size_t)DMODEL * DMODEL * 2;
    ushort* ath  = (ushort*)ws; ws += (size_t)L_SEQ * DMODEL * 2;    // attn out hi/lo
    ushort* atl  = (ushort*)ws; ws += (size_t)L_SEQ * DMODEL * 2;

    rope_tables_kernel<<<(L_SEQ + 255) / 256, 256, 0, stream>>>(cosT, sinT);

    split_rm_kernel<<<(L_SEQ * DMODEL) / 1024, 256, 0, stream>>>(x, xh, xl);
    split_t_kernel<<<dim3(PROJW / 32, DMODEL / 32), 256, 0, stream>>>(W_qkv, wqh, wql, DMODEL, PROJW);
    split_t_kernel<<<dim3(DMODEL / 32, DMODEL / 32), 256, 0, stream>>>(W_out, woh, wol, DMODEL, DMODEL);

    // proj = x @ W_qkv   (M=2048, N=3072, K=2048)
    gemm_bf16x2_kernel<<<dim3(PROJW / 128, L_SEQ / 128), 256, 0, stream>>>(
        xh, xl, wqh, wql, proj, L_SEQ, PROJW, DMODEL);

    rope_apply_kernel<<<L_SEQ, 256, 0, stream>>>(proj, cosT, sinT);

    attn_kernel<<<dim3(L_SEQ / 64, NQH), 256, 0, stream>>>(proj, s, ath, atl);

    // out = attn @ W_out  (M=2048, N=2048, K=2048)
    gemm_bf16x2_kernel<<<dim3(DMODEL / 128, L_SEQ / 128), 256, 0, stream>>>(
        ath, atl, woh, wol, outp, L_SEQ, DMODEL, DMODEL);
}

// Round 4
// 533.611 us; speedup vs baseline: 1.9581x; 1.9581x over previous
//
#include <hip/hip_runtime.h>
#include <hip/hip_bf16.h>
#include <math.h>

#define L_SEQ 2048
#define DMODEL 2048
#define PROJW 3072
#define NQH 32
#define NKVH 8
#define HD 64
#define SW 512

typedef __attribute__((ext_vector_type(8))) short bf16x8;
typedef __attribute__((ext_vector_type(4))) float f32x4;

__device__ __forceinline__ ushort f2bf(float x) {
    __hip_bfloat16 h = __float2bfloat16(x);
    return *reinterpret_cast<ushort*>(&h);
}
__device__ __forceinline__ float bf2f(ushort u) {
    __hip_bfloat16 h = *reinterpret_cast<__hip_bfloat16*>(&u);
    return __bfloat162float(h);
}

__device__ __forceinline__ void glds16(const void* g, void* l) {
    __builtin_amdgcn_global_load_lds(
        (__attribute__((address_space(1))) void*)(void*)g,
        (__attribute__((address_space(3))) void*)l, 16, 0, 0);
}

// ---------------- RoPE tables: cos/sin (L x 32) ----------------
__global__ void rope_tables_kernel(float* __restrict__ cosT, float* __restrict__ sinT) {
    int pos = blockIdx.x * blockDim.x + threadIdx.x;
    if (pos >= L_SEQ) return;
    #pragma unroll
    for (int j = 0; j < 32; ++j) {
        float c, s;
        if (j < 16) {
            float t = (float)j * (1.0f / 15.0f);
            float freq = powf(1.0f / 1024.0f, t);
            float th = (float)pos * freq;
            sincosf(th, &s, &c);
        } else {
            c = 1.0f; s = 0.0f;
        }
        cosT[pos * 32 + j] = c;
        sinT[pos * 32 + j] = s;
    }
}

// ---------------- fp32 -> bf16 hi/lo split, same layout ----------------
__global__ __launch_bounds__(256) void split_rm_kernel(const float* __restrict__ A,
                                                       ushort* __restrict__ hi,
                                                       ushort* __restrict__ lo) {
    int i = (blockIdx.x * 256 + threadIdx.x) * 4;
    float4 v = *reinterpret_cast<const float4*>(&A[i]);
    float vv[4] = {v.x, v.y, v.z, v.w};
    ushort h[4], l[4];
    #pragma unroll
    for (int j = 0; j < 4; ++j) {
        h[j] = f2bf(vv[j]);
        l[j] = f2bf(vv[j] - bf2f(h[j]));
    }
    *reinterpret_cast<ushort4*>(&hi[i]) = make_ushort4(h[0], h[1], h[2], h[3]);
    *reinterpret_cast<ushort4*>(&lo[i]) = make_ushort4(l[0], l[1], l[2], l[3]);
}

// ---------------- fp32 W(KxN) -> bf16 hi/lo transposed Wt(NxK) ----------------
__global__ __launch_bounds__(256) void split_t_kernel(const float* __restrict__ W,
                                                      ushort* __restrict__ hi,
                                                      ushort* __restrict__ lo,
                                                      int K, int N) {
    __shared__ float t[32][33];
    int n0 = blockIdx.x * 32, k0 = blockIdx.y * 32;
    int tx = threadIdx.x & 31, ty = threadIdx.x >> 5;   // ty 0..7
    #pragma unroll
    for (int r = 0; r < 32; r += 8)
        t[ty + r][tx] = W[(size_t)(k0 + ty + r) * N + n0 + tx];
    __syncthreads();
    #pragma unroll
    for (int r = 0; r < 32; r += 8) {
        float v = t[tx][ty + r];                        // = W[k0+tx][n0+ty+r]
        ushort h = f2bf(v);
        ushort l = f2bf(v - bf2f(h));
        size_t o = (size_t)(n0 + ty + r) * K + k0 + tx; // Wt[n][k]
        hi[o] = h;
        lo[o] = l;
    }
}

// ---------------- bf16x2 MFMA GEMM (unchanged, validated round 2) --------
#define GBK 32

__global__ __launch_bounds__(256) void gemm_bf16x2_kernel(
    const ushort* __restrict__ Ahi, const ushort* __restrict__ Alo,
    const ushort* __restrict__ Bhi, const ushort* __restrict__ Blo,
    float* __restrict__ C, int M, int N, int K)
{
    __shared__ __align__(16) ushort sAh[128 * 32];
    __shared__ __align__(16) ushort sAl[128 * 32];
    __shared__ __align__(16) ushort sBh[128 * 32];
    __shared__ __align__(16) ushort sBl[128 * 32];

    const int tid = threadIdx.x;
    const int w = tid >> 6, lane = tid & 63;
    const int bm = blockIdx.y * 128, bn = blockIdx.x * 128;
    const int wr = w >> 1, wc = w & 1;

    f32x4 acc[4][4];
    #pragma unroll
    for (int i = 0; i < 4; ++i)
        #pragma unroll
        for (int j = 0; j < 4; ++j)
            acc[i][j] = (f32x4){0.0f, 0.0f, 0.0f, 0.0f};

    const int q0 = w * 128 + lane;
    const int q1 = q0 + 64;
    const int r0 = q0 >> 2, r1 = q1 >> 2;
    const int ks0 = ((q0 & 3) ^ (r0 & 3)) * 8;
    const int ks1 = ((q1 & 3) ^ (r1 & 3)) * 8;
    const ushort* gAh0 = Ahi + (size_t)(bm + r0) * K + ks0;
    const ushort* gAh1 = Ahi + (size_t)(bm + r1) * K + ks1;
    const ushort* gAl0 = Alo + (size_t)(bm + r0) * K + ks0;
    const ushort* gAl1 = Alo + (size_t)(bm + r1) * K + ks1;
    const ushort* gBh0 = Bhi + (size_t)(bn + r0) * K + ks0;
    const ushort* gBh1 = Bhi + (size_t)(bn + r1) * K + ks1;
    const ushort* gBl0 = Blo + (size_t)(bn + r0) * K + ks0;
    const ushort* gBl1 = Blo + (size_t)(bn + r1) * K + ks1;
    ushort* dAh0 = sAh + (w * 2 + 0) * 512;
    ushort* dAh1 = sAh + (w * 2 + 1) * 512;
    ushort* dAl0 = sAl + (w * 2 + 0) * 512;
    ushort* dAl1 = sAl + (w * 2 + 1) * 512;
    ushort* dBh0 = sBh + (w * 2 + 0) * 512;
    ushort* dBh1 = sBh + (w * 2 + 1) * 512;
    ushort* dBl0 = sBl + (w * 2 + 0) * 512;
    ushort* dBl1 = sBl + (w * 2 + 1) * 512;

    const int kg = lane >> 4;
    const int fr = lane & 15;

    for (int k0 = 0; k0 < K; k0 += GBK) {
        __syncthreads();
        glds16(gAh0 + k0, dAh0);
        glds16(gAh1 + k0, dAh1);
        glds16(gBh0 + k0, dBh0);
        glds16(gBh1 + k0, dBh1);
        glds16(gAl0 + k0, dAl0);
        glds16(gAl1 + k0, dAl1);
        glds16(gBl0 + k0, dBl0);
        glds16(gBl1 + k0, dBl1);
        __syncthreads();

        bf16x8 ah[4], al[4], bh[4], bl[4];
        #pragma unroll
        for (int i = 0; i < 4; ++i) {
            int row = wr * 64 + i * 16 + fr;
            int off = row * 32 + ((kg ^ (row & 3)) * 8);
            ah[i] = *reinterpret_cast<const bf16x8*>(&sAh[off]);
            al[i] = *reinterpret_cast<const bf16x8*>(&sAl[off]);
        }
        #pragma unroll
        for (int j = 0; j < 4; ++j) {
            int row = wc * 64 + j * 16 + fr;
            int off = row * 32 + ((kg ^ (row & 3)) * 8);
            bh[j] = *reinterpret_cast<const bf16x8*>(&sBh[off]);
            bl[j] = *reinterpret_cast<const bf16x8*>(&sBl[off]);
        }
        #pragma unroll
        for (int i = 0; i < 4; ++i)
            #pragma unroll
            for (int j = 0; j < 4; ++j) {
                acc[i][j] = __builtin_amdgcn_mfma_f32_16x16x32_bf16(ah[i], bh[j], acc[i][j], 0, 0, 0);
                acc[i][j] = __builtin_amdgcn_mfma_f32_16x16x32_bf16(ah[i], bl[j], acc[i][j], 0, 0, 0);
                acc[i][j] = __builtin_amdgcn_mfma_f32_16x16x32_bf16(al[i], bh[j], acc[i][j], 0, 0, 0);
            }
    }

    const int rq = (lane >> 4) * 4;
    #pragma unroll
    for (int i = 0; i < 4; ++i)
        #pragma unroll
        for (int j = 0; j < 4; ++j) {
            #pragma unroll
            for (int q = 0; q < 4; ++q) {
                C[(size_t)(bm + wr * 64 + i * 16 + rq + q) * N + bn + wc * 64 + j * 16 + fr]
                    = acc[i][j][q];
            }
        }
}

// ---------------- prep: RoPE + hi/lo split of Q,K into head-major layouts --------
// Qh/Ql: [NQH][L][64], Kh/Kl: [NKVH][L][64]
__global__ __launch_bounds__(256) void prep_qk_kernel(
    const float* __restrict__ proj,
    const float* __restrict__ cosT, const float* __restrict__ sinT,
    ushort* __restrict__ Qh, ushort* __restrict__ Ql,
    ushort* __restrict__ Kh, ushort* __restrict__ Kl)
{
    int pos = blockIdx.x;
    const float* row = proj + (size_t)pos * PROJW;
    const float* ct = cosT + pos * 32;
    const float* st = sinT + pos * 32;
    int t = threadIdx.x;
    #pragma unroll
    for (int it = 0; it < 4; ++it) {            // 1024 q pairs
        int p = t + it * 256;
        int head = p >> 5, d = p & 31;
        float x1 = row[head * HD + d], x2 = row[head * HD + d + 32];
        float c = ct[d], s = st[d];
        float y1 = x1 * c + x2 * s;
        float y2 = -x1 * s + x2 * c;
        size_t o = ((size_t)head * L_SEQ + pos) * HD + d;
        ushort h1 = f2bf(y1); Qh[o] = h1;      Ql[o] = f2bf(y1 - bf2f(h1));
        ushort h2 = f2bf(y2); Qh[o + 32] = h2; Ql[o + 32] = f2bf(y2 - bf2f(h2));
    }
    {                                            // 256 k pairs
        int head = t >> 5, d = t & 31;
        float x1 = row[DMODEL + head * HD + d], x2 = row[DMODEL + head * HD + d + 32];
        float c = ct[d], s = st[d];
        float y1 = x1 * c + x2 * s;
        float y2 = -x1 * s + x2 * c;
        size_t o = ((size_t)head * L_SEQ + pos) * HD + d;
        ushort h1 = f2bf(y1); Kh[o] = h1;      Kl[o] = f2bf(y1 - bf2f(h1));
        ushort h2 = f2bf(y2); Kh[o + 32] = h2; Kl[o + 32] = f2bf(y2 - bf2f(h2));
    }
}

// ---------------- prep: V transpose + hi/lo split. Vth/Vtl: [NKVH][64][L] --------
__global__ __launch_bounds__(256) void prep_v_kernel(const float* __restrict__ proj,
                                                     ushort* __restrict__ Vth,
                                                     ushort* __restrict__ Vtl)
{
    __shared__ float tile[64][65];
    int h = blockIdx.y, p0 = blockIdx.x * 64;
    int t = threadIdx.x;
    {   // read 64 pos x 64 d, coalesced
        int r = t >> 2, c0 = (t & 3) * 16;
        const float* src = proj + (size_t)(p0 + r) * PROJW + DMODEL + NKVH * HD + h * HD + c0;
        #pragma unroll
        for (int i = 0; i < 16; i += 4) {
            float4 v = *reinterpret_cast<const float4*>(src + i);
            tile[r][c0 + i + 0] = v.x;
            tile[r][c0 + i + 1] = v.y;
            tile[r][c0 + i + 2] = v.z;
            tile[r][c0 + i + 3] = v.w;
        }
    }
    __syncthreads();
    {   // write transposed: thread owns (d, 16-pos chunk)
        int d = t >> 2, c0 = (t & 3) * 16;
        ushort hh[16], ll[16];
        #pragma unroll
        for (int i = 0; i < 16; ++i) {
            float v = tile[c0 + i][d];
            hh[i] = f2bf(v);
            ll[i] = f2bf(v - bf2f(hh[i]));
        }
        size_t o = ((size_t)h * HD + d) * L_SEQ + p0 + c0;
        #pragma unroll
        for (int i = 0; i < 16; i += 4) {
            *reinterpret_cast<ushort4*>(&Vth[o + i]) = make_ushort4(hh[i], hh[i+1], hh[i+2], hh[i+3]);
            *reinterpret_cast<ushort4*>(&Vtl[o + i]) = make_ushort4(ll[i], ll[i+1], ll[i+2], ll[i+3]);
        }
    }
}

// ---------------- MFMA flash attention (swapped operands, bf16x2 compensated) ----
// grid (L/32, NKVH), 256 thr = 4 waves; wave w handles q-head h*4+w, rows q0..q0+31.
// S^T = K*Q^T (M=64 keys, N=32 q, K=64 d); O^T = V^T*P^T (M=64 d, N=32 q, K=64 keys).
// Online softmax seeded m=sink, l=1. Inverted mask: masked iff (q>=k && q<k+SW).
__global__ __launch_bounds__(256, 2) void attn_mfma_kernel(
    const ushort* __restrict__ Qh, const ushort* __restrict__ Ql,
    const ushort* __restrict__ Kh, const ushort* __restrict__ Kl,
    const ushort* __restrict__ Vth, const ushort* __restrict__ Vtl,
    const float* __restrict__ sink,
    ushort* __restrict__ out_hi, ushort* __restrict__ out_lo)
{
    __shared__ ushort Pth[4][32][72];   // padded rows: 144B (stride/4=9 odd -> uniform banks)
    __shared__ ushort Ptl[4][32][72];

    const int tid = threadIdx.x;
    const int w = tid >> 6, lane = tid & 63;
    const int fr = lane & 15, g = lane >> 4;
    const int q0 = blockIdx.x * 32;
    const int h = blockIdx.y;
    const int hq = h * 4 + w;

    const ushort* Qb_h = Qh + ((size_t)hq * L_SEQ + q0) * HD;
    const ushort* Qb_l = Ql + ((size_t)hq * L_SEQ + q0) * HD;
    const ushort* Kb_h = Kh + (size_t)h * L_SEQ * HD;
    const ushort* Kb_l = Kl + (size_t)h * L_SEQ * HD;
    const ushort* Vb_h = Vth + (size_t)h * HD * L_SEQ;
    const ushort* Vb_l = Vtl + (size_t)h * HD * L_SEQ;

    // Q B-frags [j][kc]: col q = j*16+fr, k-dim = kc*32+g*8+e
    bf16x8 qbh[2][2], qbl[2][2];
    #pragma unroll
    for (int j = 0; j < 2; ++j)
        #pragma unroll
        for (int kc = 0; kc < 2; ++kc) {
            size_t o = (size_t)(j * 16 + fr) * HD + kc * 32 + g * 8;
            qbh[j][kc] = *reinterpret_cast<const bf16x8*>(Qb_h + o);
            qbl[j][kc] = *reinterpret_cast<const bf16x8*>(Qb_l + o);
        }

    const float sval = sink[hq];
    float m[2] = {sval, sval};
    float l[2] = {1.0f, 1.0f};
    f32x4 ot[4][2];
    #pragma unroll
    for (int i = 0; i < 4; ++i)
        #pragma unroll
        for (int j = 0; j < 2; ++j)
            ot[i][j] = (f32x4){0.0f, 0.0f, 0.0f, 0.0f};

    for (int k0 = 0; k0 < L_SEQ; k0 += 64) {
        // all-masked tile -> skip
        if ((q0 >= k0 + 63) && (q0 + 31 < k0 + SW)) continue;

        // K A-frags: row key = i*16+fr, k-dim = kc*32+g*8+e
        bf16x8 kah[4][2], kal[4][2];
        #pragma unroll
        for (int i = 0; i < 4; ++i)
            #pragma unroll
            for (int kc = 0; kc < 2; ++kc) {
                size_t o = (size_t)(k0 + i * 16 + fr) * HD + kc * 32 + g * 8;
                kah[i][kc] = *reinterpret_cast<const bf16x8*>(Kb_h + o);
                kal[i][kc] = *reinterpret_cast<const bf16x8*>(Kb_l + o);
            }

        f32x4 st4[4][2];
        #pragma unroll
        for (int i = 0; i < 4; ++i)
            #pragma unroll
            for (int j = 0; j < 2; ++j)
                st4[i][j] = (f32x4){0.0f, 0.0f, 0.0f, 0.0f};
        #pragma unroll
        for (int i = 0; i < 4; ++i)
            #pragma unroll
            for (int j = 0; j < 2; ++j)
                #pragma unroll
                for (int kc = 0; kc < 2; ++kc) {
                    st4[i][j] = __builtin_amdgcn_mfma_f32_16x16x32_bf16(kah[i][kc], qbh[j][kc], st4[i][j], 0, 0, 0);
                    st4[i][j] = __builtin_amdgcn_mfma_f32_16x16x32_bf16(kah[i][kc], qbl[j][kc], st4[i][j], 0, 0, 0);
                    st4[i][j] = __builtin_amdgcn_mfma_f32_16x16x32_bf16(kal[i][kc], qbh[j][kc], st4[i][j], 0, 0, 0);
                }

        // V A-frags (issue now; latency hides under softmax): row d = i*16+fr, k = key
        bf16x8 vah[4][2], val[4][2];
        #pragma unroll
        for (int i = 0; i < 4; ++i)
            #pragma unroll
            for (int kc = 0; kc < 2; ++kc) {
                size_t o = (size_t)(i * 16 + fr) * L_SEQ + k0 + kc * 32 + g * 8;
                vah[i][kc] = *reinterpret_cast<const bf16x8*>(Vb_h + o);
                val[i][kc] = *reinterpret_cast<const bf16x8*>(Vb_l + o);
            }

        // softmax: lane owns q = j*16+fr; keys i*16+g*4+r in-lane, rest in lanes ^16,^32
        #pragma unroll
        for (int j = 0; j < 2; ++j) {
            int q = q0 + j * 16 + fr;
            float tm = -INFINITY;
            #pragma unroll
            for (int i = 0; i < 4; ++i)
                #pragma unroll
                for (int r = 0; r < 4; ++r) {
                    int k = k0 + i * 16 + g * 4 + r;
                    float s = st4[i][j][r] * 0.125f;
                    if ((q >= k) && (q < k + SW)) s = -INFINITY;
                    st4[i][j][r] = s;
                    tm = fmaxf(tm, s);
                }
            tm = fmaxf(tm, __shfl_xor(tm, 16));
            tm = fmaxf(tm, __shfl_xor(tm, 32));
            float nm = fmaxf(m[j], tm);
            float al = __expf(m[j] - nm);
            float ps = 0.0f;
            #pragma unroll
            for (int i = 0; i < 4; ++i)
                #pragma unroll
                for (int r = 0; r < 4; ++r) {
                    float p = __expf(st4[i][j][r] - nm);
                    st4[i][j][r] = p;
                    ps += p;
                }
            ps += __shfl_xor(ps, 16);
            ps += __shfl_xor(ps, 32);
            l[j] = l[j] * al + ps;
            m[j] = nm;
            #pragma unroll
            for (int i = 0; i < 4; ++i) ot[i][j] *= al;

            // P -> LDS (hi/lo), 4 consecutive keys per 8B write
            #pragma unroll
            for (int i = 0; i < 4; ++i) {
                ushort ph[4], pl[4];
                #pragma unroll
                for (int r = 0; r < 4; ++r) {
                    float p = st4[i][j][r];
                    ph[r] = f2bf(p);
                    pl[r] = f2bf(p - bf2f(ph[r]));
                }
                *reinterpret_cast<ushort4*>(&Pth[w][j * 16 + fr][i * 16 + g * 4])
                    = make_ushort4(ph[0], ph[1], ph[2], ph[3]);
                *reinterpret_cast<ushort4*>(&Ptl[w][j * 16 + fr][i * 16 + g * 4])
                    = make_ushort4(pl[0], pl[1], pl[2], pl[3]);
            }
        }

        // P^T B-frags: col q = j*16+fr, k = key = kc*32+g*8+e
        bf16x8 pbh[2][2], pbl[2][2];
        #pragma unroll
        for (int j = 0; j < 2; ++j)
            #pragma unroll
            for (int kc = 0; kc < 2; ++kc) {
                pbh[j][kc] = *reinterpret_cast<const bf16x8*>(&Pth[w][j * 16 + fr][kc * 32 + g * 8]);
                pbl[j][kc] = *reinterpret_cast<const bf16x8*>(&Ptl[w][j * 16 + fr][kc * 32 + g * 8]);
            }

        #pragma unroll
        for (int i = 0; i < 4; ++i)
            #pragma unroll
            for (int j = 0; j < 2; ++j)
                #pragma unroll
                for (int kc = 0; kc < 2; ++kc) {
                    ot[i][j] = __builtin_amdgcn_mfma_f32_16x16x32_bf16(vah[i][kc], pbh[j][kc], ot[i][j], 0, 0, 0);
                    ot[i][j] = __builtin_amdgcn_mfma_f32_16x16x32_bf16(vah[i][kc], pbl[j][kc], ot[i][j], 0, 0, 0);
                    ot[i][j] = __builtin_amdgcn_mfma_f32_16x16x32_bf16(val[i][kc], pbh[j][kc], ot[i][j], 0, 0, 0);
                }
    }

    // epilogue: O^T frag -> out[q][hq*64+d] hi/lo; d = i*16+g*4+r, q = q0+j*16+fr
    #pragma unroll
    for (int j = 0; j < 2; ++j) {
        float inv = 1.0f / l[j];
        int q = q0 + j * 16 + fr;
        #pragma unroll
        for (int i = 0; i < 4; ++i) {
            ushort hh[4], ll[4];
            #pragma unroll
            for (int r = 0; r < 4; ++r) {
                float v = ot[i][j][r] * inv;
                hh[r] = f2bf(v);
                ll[r] = f2bf(v - bf2f(hh[r]));
            }
            size_t o = (size_t)q * DMODEL + hq * HD + i * 16 + g * 4;
            *reinterpret_cast<ushort4*>(&out_hi[o]) = make_ushort4(hh[0], hh[1], hh[2], hh[3]);
            *reinterpret_cast<ushort4*>(&out_lo[o]) = make_ushort4(ll[0], ll[1], ll[2], ll[3]);
        }
    }
}

extern "C" void kernel_launch(void* const* d_in, const int* in_sizes, int n_in,
                              void* d_out, int out_size, void* d_ws, size_t ws_size,
                              hipStream_t stream) {
    const float* x     = (const float*)d_in[0];
    const float* W_qkv = (const float*)d_in[1];
    const float* W_out = (const float*)d_in[2];
    const float* s     = (const float*)d_in[3];
    float* outp = (float*)d_out;

    // workspace (~93 MB) with time-disjoint aliasing:
    //   xh/xl (gemm1 A)  -> reused as Qh/Ql (attn)
    //   wqh/wql (gemm1 B) -> reused as ath/atl (attn out / gemm2 A)
    char* ws = (char*)d_ws;
    float*  proj = (float*)ws;  ws += (size_t)L_SEQ * PROJW * 4;      // 25.2 MB
    float*  cosT = (float*)ws;  ws += (size_t)L_SEQ * 32 * 4;
    float*  sinT = (float*)ws;  ws += (size_t)L_SEQ * 32 * 4;
    ushort* xh   = (ushort*)ws; ws += (size_t)L_SEQ * DMODEL * 2;     // 8.39 MB (= Qh size)
    ushort* xl   = (ushort*)ws; ws += (size_t)L_SEQ * DMODEL * 2;
    ushort* wqh  = (ushort*)ws; ws += (size_t)PROJW * DMODEL * 2;     // 12.6 MB (>= ath 8.39)
    ushort* wql  = (ushort*)ws; ws += (size_t)PROJW * DMODEL * 2;
    ushort* woh  = (ushort*)ws; ws += (size_t)DMODEL * DMODEL * 2;
    ushort* wol  = (ushort*)ws; ws += (size_t)DMODEL * DMODEL * 2;
    ushort* kh   = (ushort*)ws; ws += (size_t)NKVH * L_SEQ * HD * 2;  // 2.1 MB each
    ushort* kl   = (ushort*)ws; ws += (size_t)NKVH * L_SEQ * HD * 2;
    ushort* vth  = (ushort*)ws; ws += (size_t)NKVH * HD * L_SEQ * 2;
    ushort* vtl  = (ushort*)ws; ws += (size_t)NKVH * HD * L_SEQ * 2;

    ushort* qh  = xh;    // alias: live after gemm1 is done with xh
    ushort* ql  = xl;
    ushort* ath = wqh;   // alias: live after gemm1 is done with wqh
    ushort* atl = wql;

    rope_tables_kernel<<<(L_SEQ + 255) / 256, 256, 0, stream>>>(cosT, sinT);

    split_rm_kernel<<<(L_SEQ * DMODEL) / 1024, 256, 0, stream>>>(x, xh, xl);
    split_t_kernel<<<dim3(PROJW / 32, DMODEL / 32), 256, 0, stream>>>(W_qkv, wqh, wql, DMODEL, PROJW);
    split_t_kernel<<<dim3(DMODEL / 32, DMODEL / 32), 256, 0, stream>>>(W_out, woh, wol, DMODEL, DMODEL);

    // proj = x @ W_qkv
    gemm_bf16x2_kernel<<<dim3(PROJW / 128, L_SEQ / 128), 256, 0, stream>>>(
        xh, xl, wqh, wql, proj, L_SEQ, PROJW, DMODEL);

    // RoPE + split into head-major Q/K; transpose+split V
    prep_qk_kernel<<<L_SEQ, 256, 0, stream>>>(proj, cosT, sinT, qh, ql, kh, kl);
    prep_v_kernel<<<dim3(L_SEQ / 64, NKVH), 256, 0, stream>>>(proj, vth, vtl);

    // MFMA flash attention
    attn_mfma_kernel<<<dim3(L_SEQ / 32, NKVH), 256, 0, stream>>>(
        qh, ql, kh, kl, vth, vtl, s, ath, atl);

    // out = attn @ W_out
    gemm_bf16x2_kernel<<<dim3(DMODEL / 128, L_SEQ / 128), 256, 0, stream>>>(
        ath, atl, woh, wol, outp, L_SEQ, DMODEL, DMODEL);
}

// Round 7
// 440.580 us; speedup vs baseline: 2.3716x; 1.2112x over previous
//
#include <hip/hip_runtime.h>
#include <hip/hip_bf16.h>
#include <math.h>

#define L_SEQ 2048
#define DMODEL 2048
#define PROJW 3072
#define NQH 32
#define NKVH 8
#define HD 64
#define SW 512

typedef __attribute__((ext_vector_type(8))) short bf16x8;
typedef __attribute__((ext_vector_type(4))) float f32x4;

__device__ __forceinline__ ushort f2bf(float x) {
    __hip_bfloat16 h = __float2bfloat16(x);
    return *reinterpret_cast<ushort*>(&h);
}
__device__ __forceinline__ float bf2f(ushort u) {
    __hip_bfloat16 h = *reinterpret_cast<__hip_bfloat16*>(&u);
    return __bfloat162float(h);
}

__device__ __forceinline__ void glds16(const void* g, void* l) {
    __builtin_amdgcn_global_load_lds(
        (__attribute__((address_space(1))) void*)(void*)g,
        (__attribute__((address_space(3))) void*)l, 16, 0, 0);
}

// ---------------- RoPE tables: cos/sin (L x 32) ----------------
__global__ void rope_tables_kernel(float* __restrict__ cosT, float* __restrict__ sinT) {
    int pos = blockIdx.x * blockDim.x + threadIdx.x;
    if (pos >= L_SEQ) return;
    #pragma unroll
    for (int j = 0; j < 32; ++j) {
        float c, s;
        if (j < 16) {
            float t = (float)j * (1.0f / 15.0f);
            float freq = powf(1.0f / 1024.0f, t);
            float th = (float)pos * freq;
            sincosf(th, &s, &c);
        } else {
            c = 1.0f; s = 0.0f;
        }
        cosT[pos * 32 + j] = c;
        sinT[pos * 32 + j] = s;
    }
}

// ---------------- fp32 -> bf16 hi/lo split, same layout ----------------
__global__ __launch_bounds__(256) void split_rm_kernel(const float* __restrict__ A,
                                                       ushort* __restrict__ hi,
                                                       ushort* __restrict__ lo) {
    int i = (blockIdx.x * 256 + threadIdx.x) * 4;
    float4 v = *reinterpret_cast<const float4*>(&A[i]);
    float vv[4] = {v.x, v.y, v.z, v.w};
    ushort h[4], l[4];
    #pragma unroll
    for (int j = 0; j < 4; ++j) {
        h[j] = f2bf(vv[j]);
        l[j] = f2bf(vv[j] - bf2f(h[j]));
    }
    *reinterpret_cast<ushort4*>(&hi[i]) = make_ushort4(h[0], h[1], h[2], h[3]);
    *reinterpret_cast<ushort4*>(&lo[i]) = make_ushort4(l[0], l[1], l[2], l[3]);
}

// ---------------- fp32 W(KxN) -> bf16 hi/lo transposed Wt(NxK) ----------------
__global__ __launch_bounds__(256) void split_t_kernel(const float* __restrict__ W,
                                                      ushort* __restrict__ hi,
                                                      ushort* __restrict__ lo,
                                                      int K, int N) {
    __shared__ float t[32][33];
    int n0 = blockIdx.x * 32, k0 = blockIdx.y * 32;
    int tx = threadIdx.x & 31, ty = threadIdx.x >> 5;   // ty 0..7
    #pragma unroll
    for (int r = 0; r < 32; r += 8)
        t[ty + r][tx] = W[(size_t)(k0 + ty + r) * N + n0 + tx];
    __syncthreads();
    #pragma unroll
    for (int r = 0; r < 32; r += 8) {
        float v = t[tx][ty + r];                        // = W[k0+tx][n0+ty+r]
        ushort h = f2bf(v);
        ushort l = f2bf(v - bf2f(h));
        size_t o = (size_t)(n0 + ty + r) * K + k0 + tx; // Wt[n][k]
        hi[o] = h;
        lo[o] = l;
    }
}

// ---------------- bf16x2 MFMA GEMM (unchanged, validated round 2) --------
#define GBK 32

__global__ __launch_bounds__(256) void gemm_bf16x2_kernel(
    const ushort* __restrict__ Ahi, const ushort* __restrict__ Alo,
    const ushort* __restrict__ Bhi, const ushort* __restrict__ Blo,
    float* __restrict__ C, int M, int N, int K)
{
    __shared__ __align__(16) ushort sAh[128 * 32];
    __shared__ __align__(16) ushort sAl[128 * 32];
    __shared__ __align__(16) ushort sBh[128 * 32];
    __shared__ __align__(16) ushort sBl[128 * 32];

    const int tid = threadIdx.x;
    const int w = tid >> 6, lane = tid & 63;
    const int bm = blockIdx.y * 128, bn = blockIdx.x * 128;
    const int wr = w >> 1, wc = w & 1;

    f32x4 acc[4][4];
    #pragma unroll
    for (int i = 0; i < 4; ++i)
        #pragma unroll
        for (int j = 0; j < 4; ++j)
            acc[i][j] = (f32x4){0.0f, 0.0f, 0.0f, 0.0f};

    const int q0 = w * 128 + lane;
    const int q1 = q0 + 64;
    const int r0 = q0 >> 2, r1 = q1 >> 2;
    const int ks0 = ((q0 & 3) ^ (r0 & 3)) * 8;
    const int ks1 = ((q1 & 3) ^ (r1 & 3)) * 8;
    const ushort* gAh0 = Ahi + (size_t)(bm + r0) * K + ks0;
    const ushort* gAh1 = Ahi + (size_t)(bm + r1) * K + ks1;
    const ushort* gAl0 = Alo + (size_t)(bm + r0) * K + ks0;
    const ushort* gAl1 = Alo + (size_t)(bm + r1) * K + ks1;
    const ushort* gBh0 = Bhi + (size_t)(bn + r0) * K + ks0;
    const ushort* gBh1 = Bhi + (size_t)(bn + r1) * K + ks1;
    const ushort* gBl0 = Blo + (size_t)(bn + r0) * K + ks0;
    const ushort* gBl1 = Blo + (size_t)(bn + r1) * K + ks1;
    ushort* dAh0 = sAh + (w * 2 + 0) * 512;
    ushort* dAh1 = sAh + (w * 2 + 1) * 512;
    ushort* dAl0 = sAl + (w * 2 + 0) * 512;
    ushort* dAl1 = sAl + (w * 2 + 1) * 512;
    ushort* dBh0 = sBh + (w * 2 + 0) * 512;
    ushort* dBh1 = sBh + (w * 2 + 1) * 512;
    ushort* dBl0 = sBl + (w * 2 + 0) * 512;
    ushort* dBl1 = sBl + (w * 2 + 1) * 512;

    const int kg = lane >> 4;
    const int fr = lane & 15;

    for (int k0 = 0; k0 < K; k0 += GBK) {
        __syncthreads();
        glds16(gAh0 + k0, dAh0);
        glds16(gAh1 + k0, dAh1);
        glds16(gBh0 + k0, dBh0);
        glds16(gBh1 + k0, dBh1);
        glds16(gAl0 + k0, dAl0);
        glds16(gAl1 + k0, dAl1);
        glds16(gBl0 + k0, dBl0);
        glds16(gBl1 + k0, dBl1);
        __syncthreads();

        bf16x8 ah[4], al[4], bh[4], bl[4];
        #pragma unroll
        for (int i = 0; i < 4; ++i) {
            int row = wr * 64 + i * 16 + fr;
            int off = row * 32 + ((kg ^ (row & 3)) * 8);
            ah[i] = *reinterpret_cast<const bf16x8*>(&sAh[off]);
            al[i] = *reinterpret_cast<const bf16x8*>(&sAl[off]);
        }
        #pragma unroll
        for (int j = 0; j < 4; ++j) {
            int row = wc * 64 + j * 16 + fr;
            int off = row * 32 + ((kg ^ (row & 3)) * 8);
            bh[j] = *reinterpret_cast<const bf16x8*>(&sBh[off]);
            bl[j] = *reinterpret_cast<const bf16x8*>(&sBl[off]);
        }
        #pragma unroll
        for (int i = 0; i < 4; ++i)
            #pragma unroll
            for (int j = 0; j < 4; ++j) {
                acc[i][j] = __builtin_amdgcn_mfma_f32_16x16x32_bf16(ah[i], bh[j], acc[i][j], 0, 0, 0);
                acc[i][j] = __builtin_amdgcn_mfma_f32_16x16x32_bf16(ah[i], bl[j], acc[i][j], 0, 0, 0);
                acc[i][j] = __builtin_amdgcn_mfma_f32_16x16x32_bf16(al[i], bh[j], acc[i][j], 0, 0, 0);
            }
    }

    const int rq = (lane >> 4) * 4;
    #pragma unroll
    for (int i = 0; i < 4; ++i)
        #pragma unroll
        for (int j = 0; j < 4; ++j) {
            #pragma unroll
            for (int q = 0; q < 4; ++q) {
                C[(size_t)(bm + wr * 64 + i * 16 + rq + q) * N + bn + wc * 64 + j * 16 + fr]
                    = acc[i][j][q];
            }
        }
}

// ---------------- prep: RoPE + hi/lo split of Q,K into head-major layouts --------
// Q is pre-scaled by sm_scale = 0.125 (exact pow2). Qh/Ql: [NQH][L][64], Kh/Kl: [NKVH][L][64]
__global__ __launch_bounds__(256) void prep_qk_kernel(
    const float* __restrict__ proj,
    const float* __restrict__ cosT, const float* __restrict__ sinT,
    ushort* __restrict__ Qh, ushort* __restrict__ Ql,
    ushort* __restrict__ Kh, ushort* __restrict__ Kl)
{
    int pos = blockIdx.x;
    const float* row = proj + (size_t)pos * PROJW;
    const float* ct = cosT + pos * 32;
    const float* st = sinT + pos * 32;
    int t = threadIdx.x;
    #pragma unroll
    for (int it = 0; it < 4; ++it) {            // 1024 q pairs
        int p = t + it * 256;
        int head = p >> 5, d = p & 31;
        float x1 = row[head * HD + d], x2 = row[head * HD + d + 32];
        float c = ct[d], s = st[d];
        float y1 = (x1 * c + x2 * s) * 0.125f;
        float y2 = (-x1 * s + x2 * c) * 0.125f;
        size_t o = ((size_t)head * L_SEQ + pos) * HD + d;
        ushort h1 = f2bf(y1); Qh[o] = h1;      Ql[o] = f2bf(y1 - bf2f(h1));
        ushort h2 = f2bf(y2); Qh[o + 32] = h2; Ql[o + 32] = f2bf(y2 - bf2f(h2));
    }
    {                                            // 256 k pairs
        int head = t >> 5, d = t & 31;
        float x1 = row[DMODEL + head * HD + d], x2 = row[DMODEL + head * HD + d + 32];
        float c = ct[d], s = st[d];
        float y1 = x1 * c + x2 * s;
        float y2 = -x1 * s + x2 * c;
        size_t o = ((size_t)head * L_SEQ + pos) * HD + d;
        ushort h1 = f2bf(y1); Kh[o] = h1;      Kl[o] = f2bf(y1 - bf2f(h1));
        ushort h2 = f2bf(y2); Kh[o + 32] = h2; Kl[o + 32] = f2bf(y2 - bf2f(h2));
    }
}

// ---------------- prep: V transpose + hi/lo split. Vth/Vtl: [NKVH][64][L] --------
__global__ __launch_bounds__(256) void prep_v_kernel(const float* __restrict__ proj,
                                                     ushort* __restrict__ Vth,
                                                     ushort* __restrict__ Vtl)
{
    __shared__ float tile[64][65];
    int h = blockIdx.y, p0 = blockIdx.x * 64;
    int t = threadIdx.x;
    {   // read 64 pos x 64 d, coalesced
        int r = t >> 2, c0 = (t & 3) * 16;
        const float* src = proj + (size_t)(p0 + r) * PROJW + DMODEL + NKVH * HD + h * HD + c0;
        #pragma unroll
        for (int i = 0; i < 16; i += 4) {
            float4 v = *reinterpret_cast<const float4*>(src + i);
            tile[r][c0 + i + 0] = v.x;
            tile[r][c0 + i + 1] = v.y;
            tile[r][c0 + i + 2] = v.z;
            tile[r][c0 + i + 3] = v.w;
        }
    }
    __syncthreads();
    {   // write transposed: thread owns (d, 16-pos chunk)
        int d = t >> 2, c0 = (t & 3) * 16;
        ushort hh[16], ll[16];
        #pragma unroll
        for (int i = 0; i < 16; ++i) {
            float v = tile[c0 + i][d];
            hh[i] = f2bf(v);
            ll[i] = f2bf(v - bf2f(hh[i]));
        }
        size_t o = ((size_t)h * HD + d) * L_SEQ + p0 + c0;
        #pragma unroll
        for (int i = 0; i < 16; i += 4) {
            *reinterpret_cast<ushort4*>(&Vth[o + i]) = make_ushort4(hh[i], hh[i+1], hh[i+2], hh[i+3]);
            *reinterpret_cast<ushort4*>(&Vtl[o + i]) = make_ushort4(ll[i], ll[i+1], ll[i+2], ll[i+3]);
        }
    }
}

// ---------------- MFMA flash attention v2 ----------------
// 1D grid 512: h = bid&7 (XCD affinity), q0 = (bid>>3)*32. 4 waves; wave w = head h*4+w.
// K tile staged in LDS (double-buffered, XOR-swizzled, global_load_lds), shared by 4 waves.
// Skip-aware tile list t->k0 keeps the prefetch pipeline uniform.
// S^T = K*Q^T; O^T = V^T*P^T; online softmax seeded m=sink, l=1; inverted mask.
__global__ __launch_bounds__(256, 2) void attn_mfma_kernel(
    const ushort* __restrict__ Qh, const ushort* __restrict__ Ql,
    const ushort* __restrict__ Kh, const ushort* __restrict__ Kl,
    const ushort* __restrict__ Vth, const ushort* __restrict__ Vtl,
    const float* __restrict__ sink,
    ushort* __restrict__ out_hi, ushort* __restrict__ out_lo)
{
    __shared__ __align__(16) ushort KsH[2][4096];   // 64 rows x 128B, swizzled chunks
    __shared__ __align__(16) ushort KsL[2][4096];
    __shared__ __align__(16) ushort PtH[4][2048];   // per-wave P^T: 32 rows x 128B, swizzled
    __shared__ __align__(16) ushort PtL[4][2048];

    const int tid = threadIdx.x;
    const int w = tid >> 6, lane = tid & 63;
    const int fr = lane & 15, g = lane >> 4;
    const int bid = blockIdx.x;
    const int h = bid & 7;
    const int q0 = (bid >> 3) * 32;
    const int hq = h * 4 + w;

    const ushort* Qb_h = Qh + ((size_t)hq * L_SEQ + q0) * HD;
    const ushort* Qb_l = Ql + ((size_t)hq * L_SEQ + q0) * HD;
    const ushort* Kb_h = Kh + (size_t)h * L_SEQ * HD;
    const ushort* Kb_l = Kl + (size_t)h * L_SEQ * HD;
    const ushort* Vb_h = Vth + (size_t)h * HD * L_SEQ;
    const ushort* Vb_l = Vtl + (size_t)h * HD * L_SEQ;

    // ---- skip-aware tile list: skipped k0 in [kA, kB] (fully-masked tiles) ----
    int sA = q0 - 480, sB = q0 - 63;
    int kA = (sA + 63) & ~63; if (kA < 0) kA = 0;
    int kB = sB & ~63;
    bool has_skip = (sB >= 0) && (kA <= kB);
    int n1 = has_skip ? (kA >> 6) : (L_SEQ >> 6);
    int kResume = has_skip ? (kB + 64) : 0;
    int nt = n1 + (has_skip ? ((L_SEQ - kResume) >> 6) : 0);
    #define K0_OF(t) ((t) < n1 ? (t) * 64 : kResume + ((t) - n1) * 64)

    // ---- stage K tile (hi+lo) into LDS buf: 4 glds per wave, source pre-swizzled ----
    #define STAGE_K(buf, k0s) do {                                                  \
        _Pragma("unroll")                                                           \
        for (int qi = 0; qi < 2; ++qi) {                                            \
            int gq = (w * 2 + qi) * 64 + lane;                                      \
            int srow = gq >> 3, sc = gq & 7;                                        \
            size_t soff = (size_t)((k0s) + srow) * HD + ((sc ^ (srow & 7)) * 8);    \
            glds16(Kb_h + soff, &KsH[buf][(w * 2 + qi) * 512]);                     \
            glds16(Kb_l + soff, &KsL[buf][(w * 2 + qi) * 512]);                     \
        }                                                                           \
    } while (0)

    // Q B-frags [j][kc]: col q = j*16+fr, k-dim = kc*32+g*8+e  (Q pre-scaled by 0.125)
    bf16x8 qbh[2][2], qbl[2][2];
    #pragma unroll
    for (int j = 0; j < 2; ++j)
        #pragma unroll
        for (int kc = 0; kc < 2; ++kc) {
            size_t o = (size_t)(j * 16 + fr) * HD + kc * 32 + g * 8;
            qbh[j][kc] = *reinterpret_cast<const bf16x8*>(Qb_h + o);
            qbl[j][kc] = *reinterpret_cast<const bf16x8*>(Qb_l + o);
        }

    const float sval = sink[hq];
    float m[2] = {sval, sval};
    float l[2] = {1.0f, 1.0f};
    f32x4 ot[4][2];
    #pragma unroll
    for (int i = 0; i < 4; ++i)
        #pragma unroll
        for (int j = 0; j < 2; ++j)
            ot[i][j] = (f32x4){0.0f, 0.0f, 0.0f, 0.0f};

    STAGE_K(0, K0_OF(0));
    __syncthreads();                       // drain -> K(0) resident

    for (int t = 0; t < nt; ++t) {
        const int cur = t & 1;
        if (t + 1 < nt) STAGE_K(cur ^ 1, K0_OF(t + 1));   // async prefetch next tile
        const int k0 = K0_OF(t);

        // K A-frags from LDS (swizzled read): row key = i*16+fr, chunk = kc*4+g
        bf16x8 kah[4][2], kal[4][2];
        #pragma unroll
        for (int i = 0; i < 4; ++i)
            #pragma unroll
            for (int kc = 0; kc < 2; ++kc) {
                int row = i * 16 + fr;
                int off = row * 64 + (((kc * 4 + g) ^ (row & 7)) * 8);
                kah[i][kc] = *reinterpret_cast<const bf16x8*>(&KsH[cur][off]);
                kal[i][kc] = *reinterpret_cast<const bf16x8*>(&KsL[cur][off]);
            }

        f32x4 st4[4][2];
        #pragma unroll
        for (int i = 0; i < 4; ++i)
            #pragma unroll
            for (int j = 0; j < 2; ++j)
                st4[i][j] = (f32x4){0.0f, 0.0f, 0.0f, 0.0f};
        #pragma unroll
        for (int i = 0; i < 4; ++i)
            #pragma unroll
            for (int j = 0; j < 2; ++j)
                #pragma unroll
                for (int kc = 0; kc < 2; ++kc) {
                    st4[i][j] = __builtin_amdgcn_mfma_f32_16x16x32_bf16(kah[i][kc], qbh[j][kc], st4[i][j], 0, 0, 0);
                    st4[i][j] = __builtin_amdgcn_mfma_f32_16x16x32_bf16(kah[i][kc], qbl[j][kc], st4[i][j], 0, 0, 0);
                    st4[i][j] = __builtin_amdgcn_mfma_f32_16x16x32_bf16(kal[i][kc], qbh[j][kc], st4[i][j], 0, 0, 0);
                }

        // V A-frags direct from global (latency hidden under softmax)
        bf16x8 vah[4][2], val[4][2];
        #pragma unroll
        for (int i = 0; i < 4; ++i)
            #pragma unroll
            for (int kc = 0; kc < 2; ++kc) {
                size_t o = (size_t)(i * 16 + fr) * L_SEQ + k0 + kc * 32 + g * 8;
                vah[i][kc] = *reinterpret_cast<const bf16x8*>(Vb_h + o);
                val[i][kc] = *reinterpret_cast<const bf16x8*>(Vb_l + o);
            }

        // masked iff (q>=k && q<k+SW); tiles with no maskable pair skip the clamp
        const bool need_mask = (q0 + 31 >= k0) && (q0 < k0 + 63 + SW);

        #pragma unroll
        for (int j = 0; j < 2; ++j) {
            int q = q0 + j * 16 + fr;
            float tm = -INFINITY;
            if (need_mask) {
                #pragma unroll
                for (int i = 0; i < 4; ++i)
                    #pragma unroll
                    for (int r = 0; r < 4; ++r) {
                        int k = k0 + i * 16 + g * 4 + r;
                        float s = st4[i][j][r];
                        if ((q >= k) && (q < k + SW)) s = -INFINITY;
                        st4[i][j][r] = s;
                        tm = fmaxf(tm, s);
                    }
            } else {
                #pragma unroll
                for (int i = 0; i < 4; ++i)
                    #pragma unroll
                    for (int r = 0; r < 4; ++r)
                        tm = fmaxf(tm, st4[i][j][r]);
            }
            tm = fmaxf(tm, __shfl_xor(tm, 16));
            tm = fmaxf(tm, __shfl_xor(tm, 32));
            float nm = fmaxf(m[j], tm);
            float al = __expf(m[j] - nm);
            float ps = 0.0f;
            #pragma unroll
            for (int i = 0; i < 4; ++i)
                #pragma unroll
                for (int r = 0; r < 4; ++r) {
                    float p = __expf(st4[i][j][r] - nm);
                    st4[i][j][r] = p;
                    ps += p;
                }
            ps += __shfl_xor(ps, 16);
            ps += __shfl_xor(ps, 32);
            l[j] = l[j] * al + ps;
            m[j] = nm;
            #pragma unroll
            for (int i = 0; i < 4; ++i) ot[i][j] *= al;

            // P -> LDS (hi/lo), swizzled 128B rows; row = j*16+fr, key = i*16+g*4+r
            int prow = j * 16 + fr;
            #pragma unroll
            for (int i = 0; i < 4; ++i) {
                ushort ph[4], pl[4];
                #pragma unroll
                for (int r = 0; r < 4; ++r) {
                    float p = st4[i][j][r];
                    ph[r] = f2bf(p);
                    pl[r] = f2bf(p - bf2f(ph[r]));
                }
                int pc = (i * 2 + (g >> 1)) ^ (prow & 7);
                int poff = prow * 64 + pc * 8 + (g & 1) * 4;
                *reinterpret_cast<ushort4*>(&PtH[w][poff]) = make_ushort4(ph[0], ph[1], ph[2], ph[3]);
                *reinterpret_cast<ushort4*>(&PtL[w][poff]) = make_ushort4(pl[0], pl[1], pl[2], pl[3]);
            }
        }

        // P^T B-frags (swizzled read): col q = j*16+fr, chunk = kc*4+g
        bf16x8 pbh[2][2], pbl[2][2];
        #pragma unroll
        for (int j = 0; j < 2; ++j)
            #pragma unroll
            for (int kc = 0; kc < 2; ++kc) {
                int prow = j * 16 + fr;
                int off = prow * 64 + (((kc * 4 + g) ^ (prow & 7)) * 8);
                pbh[j][kc] = *reinterpret_cast<const bf16x8*>(&PtH[w][off]);
                pbl[j][kc] = *reinterpret_cast<const bf16x8*>(&PtL[w][off]);
            }

        #pragma unroll
        for (int i = 0; i < 4; ++i)
            #pragma unroll
            for (int j = 0; j < 2; ++j)
                #pragma unroll
                for (int kc = 0; kc < 2; ++kc) {
                    ot[i][j] = __builtin_amdgcn_mfma_f32_16x16x32_bf16(vah[i][kc], pbh[j][kc], ot[i][j], 0, 0, 0);
                    ot[i][j] = __builtin_amdgcn_mfma_f32_16x16x32_bf16(vah[i][kc], pbl[j][kc], ot[i][j], 0, 0, 0);
                    ot[i][j] = __builtin_amdgcn_mfma_f32_16x16x32_bf16(val[i][kc], pbh[j][kc], ot[i][j], 0, 0, 0);
                }

        __syncthreads();   // K(t+1) staged; all waves done reading KsH/KsL[cur]
    }

    // epilogue: O^T frag -> out[q][hq*64+d] hi/lo; d = i*16+g*4+r, q = q0+j*16+fr
    #pragma unroll
    for (int j = 0; j < 2; ++j) {
        float inv = 1.0f / l[j];
        int q = q0 + j * 16 + fr;
        #pragma unroll
        for (int i = 0; i < 4; ++i) {
            ushort hh[4], ll[4];
            #pragma unroll
            for (int r = 0; r < 4; ++r) {
                float v = ot[i][j][r] * inv;
                hh[r] = f2bf(v);
                ll[r] = f2bf(v - bf2f(hh[r]));
            }
            size_t o = (size_t)q * DMODEL + hq * HD + i * 16 + g * 4;
            *reinterpret_cast<ushort4*>(&out_hi[o]) = make_ushort4(hh[0], hh[1], hh[2], hh[3]);
            *reinterpret_cast<ushort4*>(&out_lo[o]) = make_ushort4(ll[0], ll[1], ll[2], ll[3]);
        }
    }
    #undef STAGE_K
    #undef K0_OF
}

extern "C" void kernel_launch(void* const* d_in, const int* in_sizes, int n_in,
                              void* d_out, int out_size, void* d_ws, size_t ws_size,
                              hipStream_t stream) {
    const float* x     = (const float*)d_in[0];
    const float* W_qkv = (const float*)d_in[1];
    const float* W_out = (const float*)d_in[2];
    const float* s     = (const float*)d_in[3];
    float* outp = (float*)d_out;

    // workspace (~93 MB) with time-disjoint aliasing:
    //   xh/xl (gemm1 A)  -> reused as Qh/Ql (attn)
    //   wqh/wql (gemm1 B) -> reused as ath/atl (attn out / gemm2 A)
    char* ws = (char*)d_ws;
    float*  proj = (float*)ws;  ws += (size_t)L_SEQ * PROJW * 4;      // 25.2 MB
    float*  cosT = (float*)ws;  ws += (size_t)L_SEQ * 32 * 4;
    float*  sinT = (float*)ws;  ws += (size_t)L_SEQ * 32 * 4;
    ushort* xh   = (ushort*)ws; ws += (size_t)L_SEQ * DMODEL * 2;     // 8.39 MB (= Qh size)
    ushort* xl   = (ushort*)ws; ws += (size_t)L_SEQ * DMODEL * 2;
    ushort* wqh  = (ushort*)ws; ws += (size_t)PROJW * DMODEL * 2;     // 12.6 MB (>= ath 8.39)
    ushort* wql  = (ushort*)ws; ws += (size_t)PROJW * DMODEL * 2;
    ushort* woh  = (ushort*)ws; ws += (size_t)DMODEL * DMODEL * 2;
    ushort* wol  = (ushort*)ws; ws += (size_t)DMODEL * DMODEL * 2;
    ushort* kh   = (ushort*)ws; ws += (size_t)NKVH * L_SEQ * HD * 2;  // 2.1 MB each
    ushort* kl   = (ushort*)ws; ws += (size_t)NKVH * L_SEQ * HD * 2;
    ushort* vth  = (ushort*)ws; ws += (size_t)NKVH * HD * L_SEQ * 2;
    ushort* vtl  = (ushort*)ws; ws += (size_t)NKVH * HD * L_SEQ * 2;

    ushort* qh  = xh;    // alias: live after gemm1 is done with xh
    ushort* ql  = xl;
    ushort* ath = wqh;   // alias: live after gemm1 is done with wqh
    ushort* atl = wql;

    rope_tables_kernel<<<(L_SEQ + 255) / 256, 256, 0, stream>>>(cosT, sinT);

    split_rm_kernel<<<(L_SEQ * DMODEL) / 1024, 256, 0, stream>>>(x, xh, xl);
    split_t_kernel<<<dim3(PROJW / 32, DMODEL / 32), 256, 0, stream>>>(W_qkv, wqh, wql, DMODEL, PROJW);
    split_t_kernel<<<dim3(DMODEL / 32, DMODEL / 32), 256, 0, stream>>>(W_out, woh, wol, DMODEL, DMODEL);

    // proj = x @ W_qkv
    gemm_bf16x2_kernel<<<dim3(PROJW / 128, L_SEQ / 128), 256, 0, stream>>>(
        xh, xl, wqh, wql, proj, L_SEQ, PROJW, DMODEL);

    // RoPE + split into head-major Q/K (Q pre-scaled); transpose+split V
    prep_qk_kernel<<<L_SEQ, 256, 0, stream>>>(proj, cosT, sinT, qh, ql, kh, kl);
    prep_v_kernel<<<dim3(L_SEQ / 64, NKVH), 256, 0, stream>>>(proj, vth, vtl);

    // MFMA flash attention v2: 1D grid, h = bid&7 for XCD L2 affinity
    attn_mfma_kernel<<<(L_SEQ / 32) * NKVH, 256, 0, stream>>>(
        qh, ql, kh, kl, vth, vtl, s, ath, atl);

    // out = attn @ W_out
    gemm_bf16x2_kernel<<<dim3(DMODEL / 128, L_SEQ / 128), 256, 0, stream>>>(
        ath, atl, woh, wol, outp, L_SEQ, DMODEL, DMODEL);
}